// Round 5
// baseline (1281.813 us; speedup 1.0000x reference)
//
#include <hip/hip_runtime.h>
#include <cstddef>
#include <cstdint>
#include <cmath>

// Problem constants
#define BDIM  64
#define SDIM  1024
#define DDIM  200
#define DPAD  224            // 7 x 32 k-steps, 14 x 16 n-tiles
#define CDIM  31
#define NSTACK 2
#define EPS   1e-5f
#define LN_N  204800.0f      // 1024*200 elements per batch LN plane

typedef __attribute__((ext_vector_type(8))) short short8;
typedef __attribute__((ext_vector_type(4))) short short4_t;
typedef __attribute__((ext_vector_type(4))) float f32x4;

__device__ __forceinline__ short f2bf(float f) {
    union { float f; unsigned u; } v; v.f = f;
    unsigned r = v.u + 0x7FFFu + ((v.u >> 16) & 1u);   // RNE
    return (short)(r >> 16);
}
__device__ __forceinline__ float bf2f(short s) {
    union { unsigned u; float f; } v; v.u = ((unsigned)(unsigned short)s) << 16;
    return v.f;
}

// ---------------- prep: padded bf16 transposed weights, biases, colsums --------
__global__ void prep_kernel(const float* __restrict__ Wp, const float* __restrict__ bp,
                            const float* __restrict__ Wm, const float* __restrict__ bm,
                            const float* __restrict__ W1, const float* __restrict__ b1,
                            const float* __restrict__ W2, const float* __restrict__ b2,
                            short* __restrict__ WtP, short* __restrict__ WtM,
                            short* __restrict__ Wt1, short* __restrict__ Wt2,
                            float* __restrict__ bpP, float* __restrict__ bmP,
                            float* __restrict__ b1P, float* __restrict__ b2P,
                            float* __restrict__ csP, float* __restrict__ cs1)
{
    int idx = blockIdx.x * 256 + threadIdx.x;
    if (idx >= DPAD * DPAD) return;
    int n = idx / DPAD, k = idx - n * DPAD;
    bool valid = (n < DDIM) && (k < DDIM);
    WtP[idx] = valid ? f2bf(Wp[(size_t)k * DDIM + n]) : 0;
    Wt1[idx] = valid ? f2bf(W1[(size_t)k * DDIM + n]) : 0;
    Wt2[idx] = valid ? f2bf(W2[(size_t)k * DDIM + n]) : 0;
    float s = 0.f;
    if (valid) {
        #pragma unroll
        for (int blk = 0; blk < 8; ++blk)
            s += Wm[(size_t)(blk * DDIM + k) * DDIM + n];
    }
    WtM[idx] = valid ? f2bf(s) : 0;
    if (idx < DPAD) {
        bpP[idx] = idx < DDIM ? bp[idx] : 0.f;
        bmP[idx] = idx < DDIM ? bm[idx] : 0.f;
        b1P[idx] = idx < DDIM ? b1[idx] : 0.f;
        b2P[idx] = idx < DDIM ? b2[idx] : 0.f;
        float sp = 0.f, s1 = 0.f;
        if (idx < DDIM) {
            for (int kk = 0; kk < DDIM; ++kk) {
                sp += bf2f(f2bf(Wp[(size_t)kk * DDIM + idx]));
                s1 += bf2f(f2bf(W1[(size_t)kk * DDIM + idx]));
            }
        }
        csP[idx] = sp;
        cs1[idx] = s1;
    }
}

// ---------------- h_bf = bf16(embed[x] + pos), zero-padded to 224 ----------------
__global__ void embed_kernel(const int* __restrict__ x, const float* __restrict__ embed,
                             const float* __restrict__ pos, short* __restrict__ h)
{
    const int row = blockIdx.x;            // b*S + s
    const int n = threadIdx.x;
    if (n >= DPAD) return;
    const int s = row & (SDIM - 1);
    const int tok = x[row];
    float v = (n < DDIM) ? embed[(size_t)tok * DDIM + n] + pos[(size_t)s * DDIM + n] : 0.f;
    h[(size_t)row * DPAD + n] = (n < DDIM) ? f2bf(v) : (short)0;
}

// ---------------- bf16 MFMA GEMM with fused LN on act (colsum trick) and res ----
__global__ __launch_bounds__(256, 2)
void gemm_bf(const short* __restrict__ act, const float* __restrict__ actParts,
             const short* __restrict__ Wt, const float* __restrict__ bias,
             const float* __restrict__ csW,
             const short* __restrict__ res, const float* __restrict__ resParts,
             short* __restrict__ out, short* __restrict__ pt,
             float* __restrict__ parts, int doRelu)
{
    const int tid  = threadIdx.x;
    const int wave = tid >> 6, lane = tid & 63;
    const int lo   = lane & 15, hi = lane >> 4;
    const int m0   = blockIdx.x * 128 + wave * 32;

    f32x4 acc[2][14];
    #pragma unroll
    for (int mt = 0; mt < 2; ++mt)
        #pragma unroll
        for (int nt = 0; nt < 14; ++nt) acc[mt][nt] = (f32x4){0.f, 0.f, 0.f, 0.f};

    #pragma unroll
    for (int ks = 0; ks < 7; ++ks) {
        short8 bfrag[2];
        #pragma unroll
        for (int mt = 0; mt < 2; ++mt)
            bfrag[mt] = *(const short8*)(act + (size_t)(m0 + mt * 16 + lo) * DPAD + ks * 32 + hi * 8);
        #pragma unroll
        for (int nt = 0; nt < 14; ++nt) {
            short8 afrag = *(const short8*)(Wt + (size_t)(nt * 16 + lo) * DPAD + ks * 32 + hi * 8);
            acc[0][nt] = __builtin_amdgcn_mfma_f32_16x16x32_bf16(afrag, bfrag[0], acc[0][nt], 0, 0, 0);
            acc[1][nt] = __builtin_amdgcn_mfma_f32_16x16x32_bf16(afrag, bfrag[1], acc[1][nt], 0, 0, 0);
        }
    }

    const int bb = (blockIdx.x * 128) >> 10;     // batch (blocks never straddle)
    float inv_a = 1.f, corr = 0.f;
    if (actParts) {
        float mean = actParts[bb * 2] / LN_N;
        inv_a = rsqrtf(actParts[bb * 2 + 1] / LN_N - mean * mean + EPS);
        corr = mean * inv_a;
    }
    float mean_r = 0.f, inv_r = 1.f;
    if (resParts) {
        mean_r = resParts[bb * 2] / LN_N;
        inv_r = rsqrtf(resParts[bb * 2 + 1] / LN_N - mean_r * mean_r + EPS);
    }

    float s = 0.f, s2 = 0.f;
    #pragma unroll
    for (int mt = 0; mt < 2; ++mt) {
        const int m = m0 + mt * 16 + lo;
        #pragma unroll
        for (int nt = 0; nt < 14; ++nt) {
            const int nb = nt * 16 + hi * 4;
            float v[4];
            #pragma unroll
            for (int r = 0; r < 4; ++r) {
                v[r] = acc[mt][nt][r] * inv_a + bias[nb + r];
                if (actParts) v[r] -= corr * csW[nb + r];
            }
            if (res) {
                short4_t rv = *(const short4_t*)(res + (size_t)m * DPAD + nb);
                #pragma unroll
                for (int r = 0; r < 4; ++r) v[r] += (bf2f(rv[r]) - mean_r) * inv_r;
            }
            if (doRelu)
                #pragma unroll
                for (int r = 0; r < 4; ++r) v[r] = fmaxf(v[r], 0.f);
            #pragma unroll
            for (int r = 0; r < 4; ++r)
                if (nb + r >= DDIM) v[r] = 0.f;      // keep pads exactly zero
            if (parts)
                #pragma unroll
                for (int r = 0; r < 4; ++r) { s += v[r]; s2 = fmaf(v[r], v[r], s2); }
            short4_t o4;
            #pragma unroll
            for (int r = 0; r < 4; ++r) o4[r] = f2bf(v[r]);
            *(short4_t*)(out + (size_t)m * DPAD + nb) = o4;
            if (pt) {
                const int sloc = m & (SDIM - 1);
                #pragma unroll
                for (int r = 0; r < 4; ++r)
                    pt[((size_t)bb * DPAD + nb + r) * SDIM + sloc] = o4[r];
            }
        }
    }

    if (parts) {
        __shared__ float rs[4], rq[4];
        #pragma unroll
        for (int off = 32; off; off >>= 1) {
            s  += __shfl_down(s, off);
            s2 += __shfl_down(s2, off);
        }
        if (lane == 0) { rs[wave] = s; rq[wave] = s2; }
        __syncthreads();
        if (tid == 0) {
            atomicAdd(&parts[bb * 2],     rs[0] + rs[1] + rs[2] + rs[3]);
            atomicAdd(&parts[bb * 2 + 1], rq[0] + rq[1] + rq[2] + rq[3]);
        }
    }
}

// ---------------- fused MFMA flash attention (bf16 in/out) ----------------
// Round-3 structure (512 blocks x 4 waves, QBLK=128, rt=2, KVBLK=64, K+Vt in LDS)
// + T14 register prefetch of next K/V tile (hides staging latency; we are
//   structurally pinned at 2 blocks/CU by unified VGPR+LDS, so regs are free)
// + exp2-domain softmax (Q pre-scaled) + T13 defer-max + setprio.
#define KSTRIDE 232
__global__ __launch_bounds__(256, 2)
void attn_kernel(const short* __restrict__ pbf, const short* __restrict__ pt,
                 short* __restrict__ c, float qscale)
{
    __shared__ short K_lds[64 * KSTRIDE];   // 29696 B; first 8192 shorts alias P
    __shared__ short Vt_lds[208 * 64];      // 26624 B

    // XCD chunk swizzle: batch b's 8 q-blocks land on one XCD
    const int bid = blockIdx.x;
    const int wg  = (bid & 7) * 64 + (bid >> 3);
    const int b   = wg >> 3;
    const int q0  = (wg & 7) * 128;

    const int tid  = threadIdx.x;
    const int wave = tid >> 6;
    const int lane = tid & 63;
    const int lo   = lane & 15;
    const int hi   = lane >> 4;

    const short* pb  = pbf + (size_t)b * SDIM * DPAD;
    const short* ptb = pt  + (size_t)b * DPAD * SDIM;

    // Q fragments, pre-scaled into exp2 domain
    short8 qf[2][7];
    #pragma unroll
    for (int rt = 0; rt < 2; ++rt)
        #pragma unroll
        for (int ks = 0; ks < 7; ++ks) {
            short8 q = *(const short8*)(pb + (size_t)(q0 + wave * 32 + rt * 16 + lo) * DPAD
                                        + ks * 32 + hi * 8);
            short8 qs;
            #pragma unroll
            for (int j = 0; j < 8; ++j) qs[j] = f2bf(bf2f(q[j]) * qscale);
            qf[rt][ks] = qs;
        }

    f32x4 o[2][13];
    float m[2][4], ell[2][4];
    #pragma unroll
    for (int rt = 0; rt < 2; ++rt) {
        #pragma unroll
        for (int n = 0; n < 13; ++n) o[rt][n] = (f32x4){0.f, 0.f, 0.f, 0.f};
        #pragma unroll
        for (int r = 0; r < 4; ++r) { m[rt][r] = -1e30f; ell[rt][r] = 0.f; }
    }

    // ---- T14 prefetch registers: next K tile (7x short8) + next Vt tile ----
    short8 kpre[7], vpre[7];
    auto load_tile = [&](int kbase) {
        #pragma unroll
        for (int u = 0; u < 7; ++u) {
            int i = u * 256 + tid;
            int r = i / 28, c8 = i - r * 28;
            kpre[u] = *(const short8*)(pb + (size_t)(kbase + r) * DPAD + c8 * 8);
        }
        #pragma unroll
        for (int u = 0; u < 7; ++u) {
            int i = u * 256 + tid;
            if (i < 1664) {
                int d = i >> 3, c8 = i & 7;
                vpre[u] = *(const short8*)(ptb + (size_t)d * SDIM + kbase + c8 * 8);
            }
        }
    };
    auto store_tile = [&]() {
        #pragma unroll
        for (int u = 0; u < 7; ++u) {
            int i = u * 256 + tid;
            int r = i / 28, c8 = i - r * 28;
            *(short8*)(&K_lds[r * KSTRIDE + c8 * 8]) = kpre[u];
        }
        #pragma unroll
        for (int u = 0; u < 7; ++u) {
            int i = u * 256 + tid;
            if (i < 1664) {
                int d = i >> 3, c8 = i & 7;
                int e = (d * 64 + c8 * 8) ^ ((d & 7) << 3);
                *(short8*)(&Vt_lds[e]) = vpre[u];
            }
        }
    };

    // prologue: stage tile 0
    load_tile(0);
    store_tile();
    __syncthreads();

    for (int kt = 0; kt < 16; ++kt) {
        const bool pf = (kt < 15);
        if (pf) load_tile((kt + 1) * 64);   // issue next-tile loads; consumed post-PV

        // QK^T (scores in log2 units via qscale)
        f32x4 sacc[2][4];
        #pragma unroll
        for (int rt = 0; rt < 2; ++rt)
            #pragma unroll
            for (int t = 0; t < 4; ++t) sacc[rt][t] = (f32x4){0.f, 0.f, 0.f, 0.f};
        __builtin_amdgcn_s_setprio(1);
        #pragma unroll
        for (int t = 0; t < 4; ++t)
            #pragma unroll
            for (int ks = 0; ks < 7; ++ks) {
                short8 kf = *(const short8*)(&K_lds[(t * 16 + lo) * KSTRIDE + ks * 32 + hi * 8]);
                sacc[0][t] = __builtin_amdgcn_mfma_f32_16x16x32_bf16(qf[0][ks], kf, sacc[0][t], 0, 0, 0);
                sacc[1][t] = __builtin_amdgcn_mfma_f32_16x16x32_bf16(qf[1][ks], kf, sacc[1][t], 0, 0, 0);
            }
        __builtin_amdgcn_s_setprio(0);
        __syncthreads();   // all waves done reading K; P may overwrite K region

        // online softmax (exp2 domain, defer-max); write P into K-alias region
        #pragma unroll
        for (int rt = 0; rt < 2; ++rt) {
            float mx[4], rsum[4];
            #pragma unroll
            for (int r = 0; r < 4; ++r)
                mx[r] = fmaxf(fmaxf(sacc[rt][0][r], sacc[rt][1][r]),
                              fmaxf(sacc[rt][2][r], sacc[rt][3][r]));
            #pragma unroll
            for (int off = 1; off <= 8; off <<= 1)
                #pragma unroll
                for (int r = 0; r < 4; ++r)
                    mx[r] = fmaxf(mx[r], __shfl_xor(mx[r], off));
            // T13: skip rescale when max growth <= 11.5 log2-units (~8 nats)
            bool need = false;
            #pragma unroll
            for (int r = 0; r < 4; ++r) need |= (mx[r] > m[rt][r] + 11.5f);
            if (__any(need)) {
                float al[4];
                #pragma unroll
                for (int r = 0; r < 4; ++r) {
                    float mn = fmaxf(m[rt][r], mx[r]);
                    al[r] = exp2f(m[rt][r] - mn);
                    m[rt][r] = mn;
                    ell[rt][r] *= al[r];
                }
                #pragma unroll
                for (int n = 0; n < 13; ++n)
                    #pragma unroll
                    for (int r = 0; r < 4; ++r) o[rt][n][r] *= al[r];
            }
            #pragma unroll
            for (int t = 0; t < 4; ++t)
                #pragma unroll
                for (int r = 0; r < 4; ++r)
                    sacc[rt][t][r] = exp2f(sacc[rt][t][r] - m[rt][r]);
            #pragma unroll
            for (int r = 0; r < 4; ++r)
                rsum[r] = sacc[rt][0][r] + sacc[rt][1][r] + sacc[rt][2][r] + sacc[rt][3][r];
            #pragma unroll
            for (int off = 1; off <= 8; off <<= 1)
                #pragma unroll
                for (int r = 0; r < 4; ++r)
                    rsum[r] += __shfl_xor(rsum[r], off);
            #pragma unroll
            for (int r = 0; r < 4; ++r) ell[rt][r] += rsum[r];
            const int pbase = wave * 2048 + rt * 1024;
            #pragma unroll
            for (int t = 0; t < 4; ++t)
                #pragma unroll
                for (int r = 0; r < 4; ++r) {
                    int qrow = hi * 4 + r;
                    int e = pbase + ((qrow * 64 + t * 16 + lo) ^ ((qrow & 7) << 3));
                    K_lds[e] = f2bf(sacc[rt][t][r]);
                }
        }

        // PV: O += P . V  (Vt fragments shared across both rt; wave-private P)
        #pragma unroll
        for (int ks2 = 0; ks2 < 2; ++ks2) {
            const int poff = (lo * 64 + ks2 * 32 + hi * 8) ^ ((lo & 7) << 3);
            short8 pa0 = *(const short8*)(&K_lds[wave * 2048 + poff]);
            short8 pa1 = *(const short8*)(&K_lds[wave * 2048 + 1024 + poff]);
            __builtin_amdgcn_s_setprio(1);
            #pragma unroll
            for (int n = 0; n < 13; ++n) {
                short8 vf = *(const short8*)(&Vt_lds[((n * 16 + lo) * 64 + ks2 * 32 + hi * 8)
                                                     ^ ((lo & 7) << 3)]);
                o[0][n] = __builtin_amdgcn_mfma_f32_16x16x32_bf16(pa0, vf, o[0][n], 0, 0, 0);
                o[1][n] = __builtin_amdgcn_mfma_f32_16x16x32_bf16(pa1, vf, o[1][n], 0, 0, 0);
            }
            __builtin_amdgcn_s_setprio(0);
        }
        __syncthreads();   // all waves done with P(K-alias) and Vt

        if (pf) {
            store_tile();      // write prefetched next tile (waitcnt auto-inserted)
            __syncthreads();
        }
    }

    // epilogue: O /= ell, store bf16 (+ zero pads 208..223)
    #pragma unroll
    for (int rt = 0; rt < 2; ++rt) {
        float inv_l[4];
        #pragma unroll
        for (int r = 0; r < 4; ++r) inv_l[r] = 1.f / ell[rt][r];
        #pragma unroll
        for (int n = 0; n < 13; ++n) {
            int dcol = n * 16 + lo;
            #pragma unroll
            for (int r = 0; r < 4; ++r) {
                size_t row = (size_t)b * SDIM + q0 + wave * 32 + rt * 16 + hi * 4 + r;
                c[row * DPAD + dcol] = f2bf(o[rt][n][r] * inv_l[r]);
            }
        }
        #pragma unroll
        for (int r = 0; r < 4; ++r) {
            size_t row = (size_t)b * SDIM + q0 + wave * 32 + rt * 16 + hi * 4 + r;
            c[row * DPAD + 208 + lo] = 0;
        }
    }
}

// ---------------- final: normalize row S-1 only + head ----------------
__global__ void final_kernel(const short* __restrict__ y, const float* __restrict__ parts,
                             const float* __restrict__ Wd, const float* __restrict__ bd,
                             float* __restrict__ out)
{
    const int b = blockIdx.x;
    const float sum = parts[b * 2], sq = parts[b * 2 + 1];
    const float mean = sum / LN_N;
    const float inv  = rsqrtf(sq / LN_N - mean * mean + EPS);
    __shared__ float hrow[DDIM];
    const short* row = y + ((size_t)b * SDIM + SDIM - 1) * DPAD;
    for (int d = threadIdx.x; d < DDIM; d += blockDim.x)
        hrow[d] = (bf2f(row[d]) - mean) * inv;
    __syncthreads();
    if (threadIdx.x < CDIM) {
        float acc = bd[threadIdx.x];
        for (int d = 0; d < DDIM; ++d)
            acc = fmaf(hrow[d], Wd[(size_t)d * CDIM + threadIdx.x], acc);
        out[(size_t)b * CDIM + threadIdx.x] = acc;
    }
}

extern "C" void kernel_launch(void* const* d_in, const int* in_sizes, int n_in,
                              void* d_out, int out_size, void* d_ws, size_t ws_size,
                              hipStream_t stream)
{
    const int*   x     = (const int*)  d_in[0];
    const float* embed = (const float*)d_in[1];
    const float* pos   = (const float*)d_in[2];
    const float* Wp    = (const float*)d_in[3];
    const float* bp    = (const float*)d_in[4];
    const float* Wm    = (const float*)d_in[5];
    const float* bm    = (const float*)d_in[6];
    const float* W1    = (const float*)d_in[7];
    const float* b1    = (const float*)d_in[8];
    const float* W2    = (const float*)d_in[9];
    const float* b2    = (const float*)d_in[10];
    const float* Wd    = (const float*)d_in[11];
    const float* bd    = (const float*)d_in[12];
    float* out = (float*)d_out;

    const size_t HB = (size_t)BDIM * SDIM * DPAD;     // 14,680,064 bf16 elems

    short* h_bf  = (short*)d_ws;
    short* p_bf  = h_bf  + HB;
    short* pt    = p_bf  + HB;
    short* cb_bf = pt    + HB;
    short* yA    = cb_bf + HB;
    short* yB    = yA    + HB;
    short* WtP   = yB + HB;
    short* WtM   = WtP + DPAD * DPAD;
    short* Wt1   = WtM + DPAD * DPAD;
    short* Wt2   = Wt1 + DPAD * DPAD;
    float* bpP   = (float*)(Wt2 + DPAD * DPAD);
    float* bmP   = bpP + DPAD;
    float* b1P   = bmP + DPAD;
    float* b2P   = b1P + DPAD;
    float* csP   = b2P + DPAD;
    float* cs1   = csP + DPAD;
    float* parts = cs1 + DPAD;                        // 4 x 64 x 2 floats
    const size_t need = (size_t)((char*)(parts + 4 * BDIM * 2) - (char*)d_ws);
    if (ws_size < need) return;

    float* pA1 = parts;
    float* pB1 = parts + BDIM * 2;
    float* pA2 = parts + 2 * BDIM * 2;
    float* pB2 = parts + 3 * BDIM * 2;

    prep_kernel<<<dim3((DPAD * DPAD + 255) / 256), dim3(256), 0, stream>>>(
        Wp, bp, Wm, bm, W1, b1, W2, b2, WtP, WtM, Wt1, Wt2, bpP, bmP, b1P, b2P, csP, cs1);
    embed_kernel<<<dim3(BDIM * SDIM), dim3(256), 0, stream>>>(x, embed, pos, h_bf);
    hipMemsetAsync(parts, 0, 4 * BDIM * 2 * sizeof(float), stream);

    const float qscale = 1.44269504f / sqrtf((float)DDIM);

    // stack 1
    gemm_bf<<<dim3(512), dim3(256), 0, stream>>>(h_bf, nullptr, WtP, bpP, nullptr,
                                                 nullptr, nullptr, p_bf, pt, nullptr, 0);
    attn_kernel<<<dim3(512), dim3(256), 0, stream>>>(p_bf, pt, cb_bf, qscale);
    gemm_bf<<<dim3(512), dim3(256), 0, stream>>>(cb_bf, nullptr, WtM, bmP, nullptr,
                                                 h_bf, nullptr, yA, nullptr, pA1, 0);
    gemm_bf<<<dim3(512), dim3(256), 0, stream>>>(yA, pA1, Wt1, b1P, cs1,
                                                 nullptr, nullptr, cb_bf, nullptr, nullptr, 1);
    gemm_bf<<<dim3(512), dim3(256), 0, stream>>>(cb_bf, nullptr, Wt2, b2P, nullptr,
                                                 yA, pA1, yB, nullptr, pB1, 0);
    // stack 2
    gemm_bf<<<dim3(512), dim3(256), 0, stream>>>(yB, pB1, WtP, bpP, csP,
                                                 nullptr, nullptr, p_bf, pt, nullptr, 0);
    attn_kernel<<<dim3(512), dim3(256), 0, stream>>>(p_bf, pt, cb_bf, qscale);
    gemm_bf<<<dim3(512), dim3(256), 0, stream>>>(cb_bf, nullptr, WtM, bmP, nullptr,
                                                 yB, pB1, h_bf, nullptr, pA2, 0);
    gemm_bf<<<dim3(512), dim3(256), 0, stream>>>(h_bf, pA2, Wt1, b1P, cs1,
                                                 nullptr, nullptr, cb_bf, nullptr, nullptr, 1);
    gemm_bf<<<dim3(512), dim3(256), 0, stream>>>(cb_bf, nullptr, Wt2, b2P, nullptr,
                                                 h_bf, pA2, yA, nullptr, pB2, 0);
    final_kernel<<<dim3(BDIM), dim3(64), 0, stream>>>(yA, pB2, Wd, bd, out);
}

// Round 6
// 614.654 us; speedup vs baseline: 2.0854x; 2.0854x over previous
//
#include <hip/hip_runtime.h>
#include <cstddef>
#include <cstdint>
#include <cmath>

// Problem constants
#define BDIM  64
#define SDIM  1024
#define DDIM  200
#define DPAD  224            // 7 x 32 k-steps, 14 x 16 n-tiles
#define PSTRIDE 232          // global row stride of p_bf (== LDS K stride, bank-friendly)
#define CDIM  31
#define NSTACK 2
#define EPS   1e-5f
#define LN_N  204800.0f      // 1024*200 elements per batch LN plane

typedef __attribute__((ext_vector_type(8))) short short8;
typedef __attribute__((ext_vector_type(4))) short short4_t;
typedef __attribute__((ext_vector_type(4))) float f32x4;

__device__ __forceinline__ short f2bf(float f) {
    union { float f; unsigned u; } v; v.f = f;
    unsigned r = v.u + 0x7FFFu + ((v.u >> 16) & 1u);   // RNE
    return (short)(r >> 16);
}
__device__ __forceinline__ float bf2f(short s) {
    union { unsigned u; float f; } v; v.u = ((unsigned)(unsigned short)s) << 16;
    return v.f;
}
__device__ __forceinline__ unsigned cvtpk_bf16(float a, float b) {
    unsigned r;
    asm volatile("v_cvt_pk_bf16_f32 %0, %1, %2" : "=v"(r) : "v"(a), "v"(b));
    return r;
}
__device__ __forceinline__ void gload_lds16(const short* g, short* l) {
    __builtin_amdgcn_global_load_lds(
        (const __attribute__((address_space(1))) void*)g,
        (__attribute__((address_space(3))) void*)l, 16, 0, 0);
}

// ---------------- prep: padded bf16 transposed weights, biases, colsums --------
__global__ void prep_kernel(const float* __restrict__ Wp, const float* __restrict__ bp,
                            const float* __restrict__ Wm, const float* __restrict__ bm,
                            const float* __restrict__ W1, const float* __restrict__ b1,
                            const float* __restrict__ W2, const float* __restrict__ b2,
                            short* __restrict__ WtP, short* __restrict__ WtM,
                            short* __restrict__ Wt1, short* __restrict__ Wt2,
                            float* __restrict__ bpP, float* __restrict__ bmP,
                            float* __restrict__ b1P, float* __restrict__ b2P,
                            float* __restrict__ csP, float* __restrict__ cs1)
{
    int idx = blockIdx.x * 256 + threadIdx.x;
    if (idx >= DPAD * DPAD) return;
    int n = idx / DPAD, k = idx - n * DPAD;
    bool valid = (n < DDIM) && (k < DDIM);
    WtP[idx] = valid ? f2bf(Wp[(size_t)k * DDIM + n]) : 0;
    Wt1[idx] = valid ? f2bf(W1[(size_t)k * DDIM + n]) : 0;
    Wt2[idx] = valid ? f2bf(W2[(size_t)k * DDIM + n]) : 0;
    float s = 0.f;
    if (valid) {
        #pragma unroll
        for (int blk = 0; blk < 8; ++blk)
            s += Wm[(size_t)(blk * DDIM + k) * DDIM + n];
    }
    WtM[idx] = valid ? f2bf(s) : 0;
    if (idx < DPAD) {
        bpP[idx] = idx < DDIM ? bp[idx] : 0.f;
        bmP[idx] = idx < DDIM ? bm[idx] : 0.f;
        b1P[idx] = idx < DDIM ? b1[idx] : 0.f;
        b2P[idx] = idx < DDIM ? b2[idx] : 0.f;
        float sp = 0.f, s1 = 0.f;
        if (idx < DDIM) {
            for (int kk = 0; kk < DDIM; ++kk) {
                sp += bf2f(f2bf(Wp[(size_t)kk * DDIM + idx]));
                s1 += bf2f(f2bf(W1[(size_t)kk * DDIM + idx]));
            }
        }
        csP[idx] = sp;
        cs1[idx] = s1;
    }
}

// ---------------- h_bf = bf16(embed[x] + pos), zero-padded to 224 ----------------
__global__ void embed_kernel(const int* __restrict__ x, const float* __restrict__ embed,
                             const float* __restrict__ pos, short* __restrict__ h)
{
    const int row = blockIdx.x;            // b*S + s
    const int n = threadIdx.x;
    if (n >= DPAD) return;
    const int s = row & (SDIM - 1);
    const int tok = x[row];
    float v = (n < DDIM) ? embed[(size_t)tok * DDIM + n] + pos[(size_t)s * DDIM + n] : 0.f;
    h[(size_t)row * DPAD + n] = (n < DDIM) ? f2bf(v) : (short)0;
}

// ---------------- bf16 MFMA GEMM with fused LN on act (colsum trick) and res ----
__global__ __launch_bounds__(256, 2)
void gemm_bf(const short* __restrict__ act, const float* __restrict__ actParts,
             const short* __restrict__ Wt, const float* __restrict__ bias,
             const float* __restrict__ csW,
             const short* __restrict__ res, const float* __restrict__ resParts,
             short* __restrict__ out, short* __restrict__ pt,
             float* __restrict__ parts, int doRelu, int outStride)
{
    const int tid  = threadIdx.x;
    const int wave = tid >> 6, lane = tid & 63;
    const int lo   = lane & 15, hi = lane >> 4;
    const int m0   = blockIdx.x * 128 + wave * 32;

    f32x4 acc[2][14];
    #pragma unroll
    for (int mt = 0; mt < 2; ++mt)
        #pragma unroll
        for (int nt = 0; nt < 14; ++nt) acc[mt][nt] = (f32x4){0.f, 0.f, 0.f, 0.f};

    #pragma unroll
    for (int ks = 0; ks < 7; ++ks) {
        short8 bfrag[2];
        #pragma unroll
        for (int mt = 0; mt < 2; ++mt)
            bfrag[mt] = *(const short8*)(act + (size_t)(m0 + mt * 16 + lo) * DPAD + ks * 32 + hi * 8);
        #pragma unroll
        for (int nt = 0; nt < 14; ++nt) {
            short8 afrag = *(const short8*)(Wt + (size_t)(nt * 16 + lo) * DPAD + ks * 32 + hi * 8);
            acc[0][nt] = __builtin_amdgcn_mfma_f32_16x16x32_bf16(afrag, bfrag[0], acc[0][nt], 0, 0, 0);
            acc[1][nt] = __builtin_amdgcn_mfma_f32_16x16x32_bf16(afrag, bfrag[1], acc[1][nt], 0, 0, 0);
        }
    }

    const int bb = (blockIdx.x * 128) >> 10;     // batch (blocks never straddle)
    float inv_a = 1.f, corr = 0.f;
    if (actParts) {
        float mean = actParts[bb * 2] / LN_N;
        inv_a = rsqrtf(actParts[bb * 2 + 1] / LN_N - mean * mean + EPS);
        corr = mean * inv_a;
    }
    float mean_r = 0.f, inv_r = 1.f;
    if (resParts) {
        mean_r = resParts[bb * 2] / LN_N;
        inv_r = rsqrtf(resParts[bb * 2 + 1] / LN_N - mean_r * mean_r + EPS);
    }

    float s = 0.f, s2 = 0.f;
    #pragma unroll
    for (int mt = 0; mt < 2; ++mt) {
        const int m = m0 + mt * 16 + lo;
        #pragma unroll
        for (int nt = 0; nt < 14; ++nt) {
            const int nb = nt * 16 + hi * 4;
            float v[4];
            #pragma unroll
            for (int r = 0; r < 4; ++r) {
                v[r] = acc[mt][nt][r] * inv_a + bias[nb + r];
                if (actParts) v[r] -= corr * csW[nb + r];
            }
            if (res) {
                short4_t rv = *(const short4_t*)(res + (size_t)m * DPAD + nb);
                #pragma unroll
                for (int r = 0; r < 4; ++r) v[r] += (bf2f(rv[r]) - mean_r) * inv_r;
            }
            if (doRelu)
                #pragma unroll
                for (int r = 0; r < 4; ++r) v[r] = fmaxf(v[r], 0.f);
            #pragma unroll
            for (int r = 0; r < 4; ++r)
                if (nb + r >= DDIM) v[r] = 0.f;      // keep pads exactly zero
            if (parts)
                #pragma unroll
                for (int r = 0; r < 4; ++r) { s += v[r]; s2 = fmaf(v[r], v[r], s2); }
            short4_t o4;
            #pragma unroll
            for (int r = 0; r < 4; ++r) o4[r] = f2bf(v[r]);
            *(short4_t*)(out + (size_t)m * outStride + nb) = o4;
            if (pt) {
                const int sloc = m & (SDIM - 1);
                #pragma unroll
                for (int r = 0; r < 4; ++r)
                    pt[((size_t)bb * DPAD + nb + r) * SDIM + sloc] = o4[r];
            }
        }
    }

    if (parts) {
        __shared__ float rs[4], rq[4];
        #pragma unroll
        for (int off = 32; off; off >>= 1) {
            s  += __shfl_down(s, off);
            s2 += __shfl_down(s2, off);
        }
        if (lane == 0) { rs[wave] = s; rq[wave] = s2; }
        __syncthreads();
        if (tid == 0) {
            atomicAdd(&parts[bb * 2],     rs[0] + rs[1] + rs[2] + rs[3]);
            atomicAdd(&parts[bb * 2 + 1], rq[0] + rq[1] + rq[2] + rq[3]);
        }
    }
}

// ---------------- fused MFMA flash attention, swapped-QK in-register softmax ----
// 512 blocks x 4 waves. Per block: 128 q-rows; per wave 32 q (2 qt-tiles of 16).
// KVBLK=32, 32 iters. K/V double-buffered in LDS via async global_load_lds
// (round-robin issuing wave, 1 barrier/iter). Swapped QK^T (mfma(K,Q)) makes
// softmax lane-local (q=lane&15); P -> PV A-frag via cvt_pk + 8 shuffles.
__global__ __launch_bounds__(256, 2)
void attn_kernel(const short* __restrict__ pbf, const short* __restrict__ pt,
                 short* __restrict__ c, float qscale)
{
    __shared__ short Kbuf[2][7680];   // 32 x 232 = 14848 B, padded to 15*1024 B
    __shared__ short Vbuf[2][6656];   // 208 x 32 (col-xor-swizzled) = 13 * 1024 B

    const int bid = blockIdx.x;
    const int wg  = (bid & 7) * 64 + (bid >> 3);   // XCD chunk swizzle
    const int b   = wg >> 3;
    const int q0  = (wg & 7) * 128;

    const int tid  = threadIdx.x;
    const int wave = tid >> 6;
    const int lane = tid & 63;
    const int lo   = lane & 15;
    const int hi   = lane >> 4;

    const short* pb  = pbf + (size_t)b * SDIM * PSTRIDE;
    const short* ptb = pt  + (size_t)b * DPAD * SDIM;

    // async stage tile kt2 -> buffers[bufIdx]; K is a verbatim contiguous copy
    // (global p_bf rows already strided 232); V source is inverse-swizzled.
    auto stage = [&](int kt2, int bufIdx) {
        const short* ks = pb + (size_t)kt2 * 32 * PSTRIDE + lane * 8;
        #pragma unroll
        for (int i = 0; i < 15; ++i)
            gload_lds16(ks + i * 512, &Kbuf[bufIdx][i * 512]);
        #pragma unroll
        for (int i = 0; i < 13; ++i) {
            int e = i * 512 + lane * 8;
            int d = e >> 5;
            int cc = (e & 31) ^ (((d >> 1) & 3) << 3);
            gload_lds16(ptb + (size_t)d * SDIM + kt2 * 32 + cc, &Vbuf[bufIdx][i * 512]);
        }
    };

    // Q fragments (2 qt x 7 ks), pre-scaled into exp2 domain
    short8 qf[2][7];
    #pragma unroll
    for (int qt = 0; qt < 2; ++qt)
        #pragma unroll
        for (int ks = 0; ks < 7; ++ks) {
            short8 q = *(const short8*)(pb + (size_t)(q0 + wave * 32 + qt * 16 + lo) * PSTRIDE
                                        + ks * 32 + hi * 8);
            short8 qs;
            #pragma unroll
            for (int j = 0; j < 8; ++j) qs[j] = f2bf(bf2f(q[j]) * qscale);
            qf[qt][ks] = qs;
        }

    f32x4 o[2][13];
    float m[2], ell[2];
    #pragma unroll
    for (int qt = 0; qt < 2; ++qt) {
        #pragma unroll
        for (int n = 0; n < 13; ++n) o[qt][n] = (f32x4){0.f, 0.f, 0.f, 0.f};
        m[qt] = -1e30f; ell[qt] = 0.f;
    }

    if (wave == 0) stage(0, 0);
    __syncthreads();

    for (int kt = 0; kt < 32; ++kt) {
        const int cur = kt & 1;
        if (kt < 31 && wave == ((kt + 1) & 3)) stage(kt + 1, cur ^ 1);

        // QK^T swapped: sacc[qt][t] = mfma(K_t, Q_qt); lane holds q=lo, k=t*16+hi*4+r
        f32x4 sacc[2][2];
        #pragma unroll
        for (int qt = 0; qt < 2; ++qt)
            #pragma unroll
            for (int t = 0; t < 2; ++t) sacc[qt][t] = (f32x4){0.f, 0.f, 0.f, 0.f};
        __builtin_amdgcn_s_setprio(1);
        #pragma unroll
        for (int t = 0; t < 2; ++t)
            #pragma unroll
            for (int ks = 0; ks < 7; ++ks) {
                short8 kf = *(const short8*)(&Kbuf[cur][(t * 16 + lo) * PSTRIDE + ks * 32 + hi * 8]);
                sacc[0][t] = __builtin_amdgcn_mfma_f32_16x16x32_bf16(kf, qf[0][ks], sacc[0][t], 0, 0, 0);
                sacc[1][t] = __builtin_amdgcn_mfma_f32_16x16x32_bf16(kf, qf[1][ks], sacc[1][t], 0, 0, 0);
            }
        __builtin_amdgcn_s_setprio(0);

        // in-register online softmax (exp2 domain, defer-max) + P->A-frag repack
        short8 pa[2];
        #pragma unroll
        for (int qt = 0; qt < 2; ++qt) {
            float mx = fmaxf(fmaxf(fmaxf(sacc[qt][0][0], sacc[qt][0][1]),
                                   fmaxf(sacc[qt][0][2], sacc[qt][0][3])),
                             fmaxf(fmaxf(sacc[qt][1][0], sacc[qt][1][1]),
                                   fmaxf(sacc[qt][1][2], sacc[qt][1][3])));
            mx = fmaxf(mx, __shfl_xor(mx, 16));
            mx = fmaxf(mx, __shfl_xor(mx, 32));
            if (__any(mx > m[qt] + 11.5f)) {          // T13 defer-max (log2 units)
                float mn = fmaxf(m[qt], mx);
                float al = exp2f(m[qt] - mn);
                m[qt] = mn; ell[qt] *= al;
                float alr[4];
                #pragma unroll
                for (int r = 0; r < 4; ++r) alr[r] = __shfl(al, hi * 4 + r);
                #pragma unroll
                for (int n = 0; n < 13; ++n)
                    #pragma unroll
                    for (int r = 0; r < 4; ++r) o[qt][n][r] *= alr[r];
            }
            float p[2][4]; float rsum = 0.f;
            #pragma unroll
            for (int t = 0; t < 2; ++t)
                #pragma unroll
                for (int r = 0; r < 4; ++r) {
                    p[t][r] = exp2f(sacc[qt][t][r] - m[qt]);
                    rsum += p[t][r];
                }
            rsum += __shfl_xor(rsum, 16);
            rsum += __shfl_xor(rsum, 32);
            ell[qt] += rsum;
            // pack own 8 P values (bf16 pairs), route to A-frag lanes:
            // target (lo,hi) k-chunk = hi*8..hi*8+7 -> t=hi>>1, sources hi'=(hi&1)*2, +1
            unsigned pk01_0 = cvtpk_bf16(p[0][0], p[0][1]);
            unsigned pk23_0 = cvtpk_bf16(p[0][2], p[0][3]);
            unsigned pk01_1 = cvtpk_bf16(p[1][0], p[1][1]);
            unsigned pk23_1 = cvtpk_bf16(p[1][2], p[1][3]);
            const int srcA = lo + ((hi & 1) * 2) * 16;
            const int srcB = srcA + 16;
            int a0 = __shfl((int)pk01_0, srcA), a1 = __shfl((int)pk01_1, srcA);
            int b0 = __shfl((int)pk23_0, srcA), b1 = __shfl((int)pk23_1, srcA);
            int c0 = __shfl((int)pk01_0, srcB), c1 = __shfl((int)pk01_1, srcB);
            int d0 = __shfl((int)pk23_0, srcB), d1 = __shfl((int)pk23_1, srcB);
            const bool thi = (hi >> 1) != 0;
            union { short8 s; int u[4]; } pu;
            pu.u[0] = thi ? a1 : a0;
            pu.u[1] = thi ? b1 : b0;
            pu.u[2] = thi ? c1 : c0;
            pu.u[3] = thi ? d1 : d0;
            pa[qt] = pu.s;
        }

        // PV: O[qt][n] += P_qt . V ; V B-frags shared across qt
        __builtin_amdgcn_s_setprio(1);
        #pragma unroll
        for (int n = 0; n < 13; ++n) {
            int d = n * 16 + lo;
            int addr = d * 32 + ((hi * 8) ^ (((d >> 1) & 3) << 3));
            short8 vf = *(const short8*)(&Vbuf[cur][addr]);
            o[0][n] = __builtin_amdgcn_mfma_f32_16x16x32_bf16(pa[0], vf, o[0][n], 0, 0, 0);
            o[1][n] = __builtin_amdgcn_mfma_f32_16x16x32_bf16(pa[1], vf, o[1][n], 0, 0, 0);
        }
        __builtin_amdgcn_s_setprio(0);

        __syncthreads();   // issuer drains vmcnt(0): next buffer published; reads done
    }

    // epilogue: O /= ell (ell lives at q=lo lanes; O rows are q=hi*4+r)
    #pragma unroll
    for (int qt = 0; qt < 2; ++qt) {
        float inv_l = 1.f / ell[qt];
        float invr[4];
        #pragma unroll
        for (int r = 0; r < 4; ++r) invr[r] = __shfl(inv_l, hi * 4 + r);
        #pragma unroll
        for (int n = 0; n < 13; ++n) {
            int dcol = n * 16 + lo;
            #pragma unroll
            for (int r = 0; r < 4; ++r) {
                size_t row = (size_t)b * SDIM + q0 + wave * 32 + qt * 16 + hi * 4 + r;
                c[row * DPAD + dcol] = f2bf(o[qt][n][r] * invr[r]);
            }
        }
        #pragma unroll
        for (int r = 0; r < 4; ++r) {
            size_t row = (size_t)b * SDIM + q0 + wave * 32 + qt * 16 + hi * 4 + r;
            c[row * DPAD + 208 + lo] = 0;
        }
    }
}

// ---------------- final: normalize row S-1 only + head ----------------
__global__ void final_kernel(const short* __restrict__ y, const float* __restrict__ parts,
                             const float* __restrict__ Wd, const float* __restrict__ bd,
                             float* __restrict__ out)
{
    const int b = blockIdx.x;
    const float sum = parts[b * 2], sq = parts[b * 2 + 1];
    const float mean = sum / LN_N;
    const float inv  = rsqrtf(sq / LN_N - mean * mean + EPS);
    __shared__ float hrow[DDIM];
    const short* row = y + ((size_t)b * SDIM + SDIM - 1) * DPAD;
    for (int d = threadIdx.x; d < DDIM; d += blockDim.x)
        hrow[d] = (bf2f(row[d]) - mean) * inv;
    __syncthreads();
    if (threadIdx.x < CDIM) {
        float acc = bd[threadIdx.x];
        for (int d = 0; d < DDIM; ++d)
            acc = fmaf(hrow[d], Wd[(size_t)d * CDIM + threadIdx.x], acc);
        out[(size_t)b * CDIM + threadIdx.x] = acc;
    }
}

extern "C" void kernel_launch(void* const* d_in, const int* in_sizes, int n_in,
                              void* d_out, int out_size, void* d_ws, size_t ws_size,
                              hipStream_t stream)
{
    const int*   x     = (const int*)  d_in[0];
    const float* embed = (const float*)d_in[1];
    const float* pos   = (const float*)d_in[2];
    const float* Wp    = (const float*)d_in[3];
    const float* bp    = (const float*)d_in[4];
    const float* Wm    = (const float*)d_in[5];
    const float* bm    = (const float*)d_in[6];
    const float* W1    = (const float*)d_in[7];
    const float* b1    = (const float*)d_in[8];
    const float* W2    = (const float*)d_in[9];
    const float* b2    = (const float*)d_in[10];
    const float* Wd    = (const float*)d_in[11];
    const float* bd    = (const float*)d_in[12];
    float* out = (float*)d_out;

    const size_t HB = (size_t)BDIM * SDIM * DPAD;     // 14,680,064 bf16 elems
    const size_t PB = (size_t)BDIM * SDIM * PSTRIDE;  // p_bf with stride 232

    short* h_bf  = (short*)d_ws;
    short* p_bf  = h_bf  + HB;
    short* pt    = p_bf  + PB;
    short* cb_bf = pt    + HB;
    short* yA    = cb_bf + HB;
    short* yB    = yA    + HB;
    short* WtP   = yB + HB;
    short* WtM   = WtP + DPAD * DPAD;
    short* Wt1   = WtM + DPAD * DPAD;
    short* Wt2   = Wt1 + DPAD * DPAD;
    float* bpP   = (float*)(Wt2 + DPAD * DPAD);
    float* bmP   = bpP + DPAD;
    float* b1P   = bmP + DPAD;
    float* b2P   = b1P + DPAD;
    float* csP   = b2P + DPAD;
    float* cs1   = csP + DPAD;
    float* parts = cs1 + DPAD;                        // 4 x 64 x 2 floats
    const size_t need = (size_t)((char*)(parts + 4 * BDIM * 2) - (char*)d_ws);
    if (ws_size < need) return;

    float* pA1 = parts;
    float* pB1 = parts + BDIM * 2;
    float* pA2 = parts + 2 * BDIM * 2;
    float* pB2 = parts + 3 * BDIM * 2;

    prep_kernel<<<dim3((DPAD * DPAD + 255) / 256), dim3(256), 0, stream>>>(
        Wp, bp, Wm, bm, W1, b1, W2, b2, WtP, WtM, Wt1, Wt2, bpP, bmP, b1P, b2P, csP, cs1);
    embed_kernel<<<dim3(BDIM * SDIM), dim3(256), 0, stream>>>(x, embed, pos, h_bf);
    hipMemsetAsync(parts, 0, 4 * BDIM * 2 * sizeof(float), stream);

    const float qscale = 1.44269504f / sqrtf((float)DDIM);

    // stack 1
    gemm_bf<<<dim3(512), dim3(256), 0, stream>>>(h_bf, nullptr, WtP, bpP, nullptr,
                                                 nullptr, nullptr, p_bf, pt, nullptr, 0, PSTRIDE);
    attn_kernel<<<dim3(512), dim3(256), 0, stream>>>(p_bf, pt, cb_bf, qscale);
    gemm_bf<<<dim3(512), dim3(256), 0, stream>>>(cb_bf, nullptr, WtM, bmP, nullptr,
                                                 h_bf, nullptr, yA, nullptr, pA1, 0, DPAD);
    gemm_bf<<<dim3(512), dim3(256), 0, stream>>>(yA, pA1, Wt1, b1P, cs1,
                                                 nullptr, nullptr, cb_bf, nullptr, nullptr, 1, DPAD);
    gemm_bf<<<dim3(512), dim3(256), 0, stream>>>(cb_bf, nullptr, Wt2, b2P, nullptr,
                                                 yA, pA1, yB, nullptr, pB1, 0, DPAD);
    // stack 2
    gemm_bf<<<dim3(512), dim3(256), 0, stream>>>(yB, pB1, WtP, bpP, csP,
                                                 nullptr, nullptr, p_bf, pt, nullptr, 0, PSTRIDE);
    attn_kernel<<<dim3(512), dim3(256), 0, stream>>>(p_bf, pt, cb_bf, qscale);
    gemm_bf<<<dim3(512), dim3(256), 0, stream>>>(cb_bf, nullptr, WtM, bmP, nullptr,
                                                 yB, pB1, h_bf, nullptr, pA2, 0, DPAD);
    gemm_bf<<<dim3(512), dim3(256), 0, stream>>>(h_bf, pA2, Wt1, b1P, cs1,
                                                 nullptr, nullptr, cb_bf, nullptr, nullptr, 1, DPAD);
    gemm_bf<<<dim3(512), dim3(256), 0, stream>>>(cb_bf, nullptr, Wt2, b2P, nullptr,
                                                 h_bf, pA2, yA, nullptr, pB2, 0, DPAD);
    final_kernel<<<dim3(BDIM), dim3(64), 0, stream>>>(yA, pB2, Wd, bd, out);
}

// Round 7
// 436.317 us; speedup vs baseline: 2.9378x; 1.4087x over previous
//
#include <hip/hip_runtime.h>
#include <cstddef>
#include <cstdint>
#include <cmath>

// Problem constants
#define BDIM  64
#define SDIM  1024
#define DDIM  200
#define DPAD  224            // 7 x 32 k-steps, 14 x 16 n-tiles
#define PSTRIDE 232          // global row stride of p_bf (== LDS K stride, bank-friendly)
#define CDIM  31
#define NSTACK 2
#define EPS   1e-5f
#define LN_N  204800.0f      // 1024*200 elements per batch LN plane

typedef __attribute__((ext_vector_type(8))) short short8;
typedef __attribute__((ext_vector_type(4))) short short4_t;
typedef __attribute__((ext_vector_type(4))) float f32x4;

__device__ __forceinline__ short f2bf(float f) {
    union { float f; unsigned u; } v; v.f = f;
    unsigned r = v.u + 0x7FFFu + ((v.u >> 16) & 1u);   // RNE
    return (short)(r >> 16);
}
__device__ __forceinline__ float bf2f(short s) {
    union { unsigned u; float f; } v; v.u = ((unsigned)(unsigned short)s) << 16;
    return v.f;
}
__device__ __forceinline__ unsigned cvtpk_bf16(float a, float b) {
    unsigned r;
    asm volatile("v_cvt_pk_bf16_f32 %0, %1, %2" : "=v"(r) : "v"(a), "v"(b));
    return r;
}
__device__ __forceinline__ void gload_lds16(const short* g, short* l) {
    __builtin_amdgcn_global_load_lds(
        (const __attribute__((address_space(1))) void*)g,
        (__attribute__((address_space(3))) void*)l, 16, 0, 0);
}

// ---------------- prep: padded bf16 transposed weights, biases, colsums --------
__global__ void prep_kernel(const float* __restrict__ Wp, const float* __restrict__ bp,
                            const float* __restrict__ Wm, const float* __restrict__ bm,
                            const float* __restrict__ W1, const float* __restrict__ b1,
                            const float* __restrict__ W2, const float* __restrict__ b2,
                            short* __restrict__ WtP, short* __restrict__ WtM,
                            short* __restrict__ Wt1, short* __restrict__ Wt2,
                            float* __restrict__ bpP, float* __restrict__ bmP,
                            float* __restrict__ b1P, float* __restrict__ b2P,
                            float* __restrict__ csP, float* __restrict__ cs1)
{
    int idx = blockIdx.x * 256 + threadIdx.x;
    if (idx >= DPAD * DPAD) return;
    int n = idx / DPAD, k = idx - n * DPAD;
    bool valid = (n < DDIM) && (k < DDIM);
    WtP[idx] = valid ? f2bf(Wp[(size_t)k * DDIM + n]) : 0;
    Wt1[idx] = valid ? f2bf(W1[(size_t)k * DDIM + n]) : 0;
    Wt2[idx] = valid ? f2bf(W2[(size_t)k * DDIM + n]) : 0;
    float s = 0.f;
    if (valid) {
        #pragma unroll
        for (int blk = 0; blk < 8; ++blk)
            s += Wm[(size_t)(blk * DDIM + k) * DDIM + n];
    }
    WtM[idx] = valid ? f2bf(s) : 0;
    if (idx < DPAD) {
        bpP[idx] = idx < DDIM ? bp[idx] : 0.f;
        bmP[idx] = idx < DDIM ? bm[idx] : 0.f;
        b1P[idx] = idx < DDIM ? b1[idx] : 0.f;
        b2P[idx] = idx < DDIM ? b2[idx] : 0.f;
        float sp = 0.f, s1 = 0.f;
        if (idx < DDIM) {
            for (int kk = 0; kk < DDIM; ++kk) {
                sp += bf2f(f2bf(Wp[(size_t)kk * DDIM + idx]));
                s1 += bf2f(f2bf(W1[(size_t)kk * DDIM + idx]));
            }
        }
        csP[idx] = sp;
        cs1[idx] = s1;
    }
}

// ---------------- h_bf = bf16(embed[x] + pos), zero-padded to 224 ----------------
__global__ void embed_kernel(const int* __restrict__ x, const float* __restrict__ embed,
                             const float* __restrict__ pos, short* __restrict__ h)
{
    const int row = blockIdx.x;            // b*S + s
    const int n = threadIdx.x;
    if (n >= DPAD) return;
    const int s = row & (SDIM - 1);
    const int tok = x[row];
    float v = (n < DDIM) ? embed[(size_t)tok * DDIM + n] + pos[(size_t)s * DDIM + n] : 0.f;
    h[(size_t)row * DPAD + n] = (n < DDIM) ? f2bf(v) : (short)0;
}

// ---------------- bf16 MFMA GEMM, LDS-staged 2-phase, fused LN ----------------
// out[M,224] = LN?(act) @ Wt^T + bias (+ LN?(res)) (+relu) (+stats)
// A-operand = act rows (m), B-operand = Wt rows (n) => C row=m (hi*4+r), col=n (lo)
// Staging: per-ks slices (Wt 224x32 = 14 chunks, act 128x32 = 8 chunks) via
// global_load_lds with slot-XOR swizzle folded into the per-lane SOURCE address;
// reads apply the same XOR -> 2-way bank-free ds_read_b128.
#define WSLICE 7168   // 224*32 shorts
#define GBUFSZ 11264  // WSLICE + 128*32
__global__ __launch_bounds__(256, 2)
void gemm_bf(const short* __restrict__ act, const float* __restrict__ actParts,
             const short* __restrict__ Wt, const float* __restrict__ bias,
             const float* __restrict__ csW,
             const short* __restrict__ res, const float* __restrict__ resParts,
             short* __restrict__ out, float* __restrict__ parts,
             int doRelu, int outStride)
{
    __shared__ short SB[2][GBUFSZ];   // 44 KB double-buffer

    const int tid  = threadIdx.x;
    const int wave = tid >> 6, lane = tid & 63;
    const int lo   = lane & 15, hi = lane >> 4;
    const int mblk = blockIdx.x * 128;

    // stage k-slice ks into SB[buf]; wave-strided chunk distribution
    auto stage = [&](int ks, int buf) {
        for (int c = wave; c < 22; c += 4) {
            if (c < 14) {
                int row = c * 16 + (lane >> 2);
                int kc  = (lane & 3) ^ ((row >> 1) & 3);
                gload_lds16(Wt + (size_t)row * DPAD + ks * 32 + kc * 8,
                            &SB[buf][c * 512 + lane * 8]);
            } else {
                int ci  = c - 14;
                int row = ci * 16 + (lane >> 2);
                int kc  = (lane & 3) ^ ((row >> 1) & 3);
                gload_lds16(act + (size_t)(mblk + row) * DPAD + ks * 32 + kc * 8,
                            &SB[buf][WSLICE + ci * 512 + lane * 8]);
            }
        }
    };

    f32x4 acc[2][14];
    #pragma unroll
    for (int mt = 0; mt < 2; ++mt)
        #pragma unroll
        for (int nt = 0; nt < 14; ++nt) acc[mt][nt] = (f32x4){0.f, 0.f, 0.f, 0.f};

    stage(0, 0);
    __syncthreads();

    #pragma unroll
    for (int ks = 0; ks < 7; ++ks) {
        const int cur = ks & 1;
        if (ks < 6) stage(ks + 1, cur ^ 1);

        short8 af[2];
        #pragma unroll
        for (int mt = 0; mt < 2; ++mt) {
            int arow = wave * 32 + mt * 16 + lo;
            af[mt] = *(const short8*)&SB[cur][WSLICE + arow * 32
                                             + ((hi * 8) ^ (((arow >> 1) & 3) << 3))];
        }
        #pragma unroll
        for (int nt = 0; nt < 14; ++nt) {
            int brow = nt * 16 + lo;
            short8 bf_ = *(const short8*)&SB[cur][brow * 32
                                                 + ((hi * 8) ^ (((brow >> 1) & 3) << 3))];
            acc[0][nt] = __builtin_amdgcn_mfma_f32_16x16x32_bf16(af[0], bf_, acc[0][nt], 0, 0, 0);
            acc[1][nt] = __builtin_amdgcn_mfma_f32_16x16x32_bf16(af[1], bf_, acc[1][nt], 0, 0, 0);
        }
        __syncthreads();
    }

    const int bb = mblk >> 10;                 // batch (blocks never straddle)
    float inv_a = 1.f, corr = 0.f;
    if (actParts) {
        float mean = actParts[bb * 2] / LN_N;
        inv_a = rsqrtf(actParts[bb * 2 + 1] / LN_N - mean * mean + EPS);
        corr = mean * inv_a;
    }
    float mean_r = 0.f, inv_r = 1.f;
    if (resParts) {
        mean_r = resParts[bb * 2] / LN_N;
        inv_r = rsqrtf(resParts[bb * 2 + 1] / LN_N - mean_r * mean_r + EPS);
    }

    float s = 0.f, s2 = 0.f;
    #pragma unroll
    for (int mt = 0; mt < 2; ++mt) {
        #pragma unroll
        for (int nt = 0; nt < 14; ++nt) {
            const int n = nt * 16 + lo;
            const float bn = bias[n];
            const float cw = actParts ? csW[n] : 0.f;
            float v[4];
            #pragma unroll
            for (int r = 0; r < 4; ++r)
                v[r] = acc[mt][nt][r] * inv_a + bn - corr * cw;
            if (res) {
                #pragma unroll
                for (int r = 0; r < 4; ++r) {
                    int m = mblk + wave * 32 + mt * 16 + hi * 4 + r;
                    v[r] += (bf2f(res[(size_t)m * DPAD + n]) - mean_r) * inv_r;
                }
            }
            if (doRelu)
                #pragma unroll
                for (int r = 0; r < 4; ++r) v[r] = fmaxf(v[r], 0.f);
            if (n >= DDIM)
                #pragma unroll
                for (int r = 0; r < 4; ++r) v[r] = 0.f;
            if (parts)
                #pragma unroll
                for (int r = 0; r < 4; ++r) { s += v[r]; s2 = fmaf(v[r], v[r], s2); }
            #pragma unroll
            for (int r = 0; r < 4; ++r) {
                int m = mblk + wave * 32 + mt * 16 + hi * 4 + r;
                out[(size_t)m * outStride + n] = f2bf(v[r]);
            }
        }
    }

    if (parts) {
        __shared__ float rs[4], rq[4];
        #pragma unroll
        for (int off = 32; off; off >>= 1) {
            s  += __shfl_down(s, off);
            s2 += __shfl_down(s2, off);
        }
        if (lane == 0) { rs[wave] = s; rq[wave] = s2; }
        __syncthreads();
        if (tid == 0) {
            atomicAdd(&parts[bb * 2],     rs[0] + rs[1] + rs[2] + rs[3]);
            atomicAdd(&parts[bb * 2 + 1], rq[0] + rq[1] + rq[2] + rq[3]);
        }
    }
}

// ---------------- transpose: pt[b][d][s] = p_bf[b][s][d]  (32x32 LDS tiles) ------
__global__ void vt_kernel(const short* __restrict__ p, short* __restrict__ pt)
{
    __shared__ short T[32][33];
    const int b  = blockIdx.z;
    const int s0 = blockIdx.x * 32;
    const int d0 = blockIdx.y * 32;
    const int t  = threadIdx.x;
    const int row = t >> 3, c4 = (t & 7) * 4;
    short4_t v = *(const short4_t*)(p + ((size_t)b * SDIM + s0 + row) * PSTRIDE + d0 + c4);
    #pragma unroll
    for (int j = 0; j < 4; ++j) T[row][c4 + j] = v[j];
    __syncthreads();
    short4_t o;
    #pragma unroll
    for (int j = 0; j < 4; ++j) o[j] = T[c4 + j][row];
    *(short4_t*)(pt + ((size_t)b * DPAD + d0 + row) * SDIM + s0 + c4) = o;
}

// ---------------- fused MFMA flash attention (unchanged from round 6) ----------
__global__ __launch_bounds__(256, 2)
void attn_kernel(const short* __restrict__ pbf, const short* __restrict__ pt,
                 short* __restrict__ c, float qscale)
{
    __shared__ short Kbuf[2][7680];   // 32 x 232
    __shared__ short Vbuf[2][6656];   // 208 x 32 (col-xor-swizzled)

    const int bid = blockIdx.x;
    const int wg  = (bid & 7) * 64 + (bid >> 3);   // XCD chunk swizzle
    const int b   = wg >> 3;
    const int q0  = (wg & 7) * 128;

    const int tid  = threadIdx.x;
    const int wave = tid >> 6;
    const int lane = tid & 63;
    const int lo   = lane & 15;
    const int hi   = lane >> 4;

    const short* pb  = pbf + (size_t)b * SDIM * PSTRIDE;
    const short* ptb = pt  + (size_t)b * DPAD * SDIM;

    auto stage = [&](int kt2, int bufIdx) {
        const short* ks = pb + (size_t)kt2 * 32 * PSTRIDE + lane * 8;
        #pragma unroll
        for (int i = 0; i < 15; ++i)
            gload_lds16(ks + i * 512, &Kbuf[bufIdx][i * 512]);
        #pragma unroll
        for (int i = 0; i < 13; ++i) {
            int e = i * 512 + lane * 8;
            int d = e >> 5;
            int cc = (e & 31) ^ (((d >> 1) & 3) << 3);
            gload_lds16(ptb + (size_t)d * SDIM + kt2 * 32 + cc, &Vbuf[bufIdx][i * 512]);
        }
    };

    short8 qf[2][7];
    #pragma unroll
    for (int qt = 0; qt < 2; ++qt)
        #pragma unroll
        for (int ks = 0; ks < 7; ++ks) {
            short8 q = *(const short8*)(pb + (size_t)(q0 + wave * 32 + qt * 16 + lo) * PSTRIDE
                                        + ks * 32 + hi * 8);
            short8 qs;
            #pragma unroll
            for (int j = 0; j < 8; ++j) qs[j] = f2bf(bf2f(q[j]) * qscale);
            qf[qt][ks] = qs;
        }

    f32x4 o[2][13];
    float m[2], ell[2];
    #pragma unroll
    for (int qt = 0; qt < 2; ++qt) {
        #pragma unroll
        for (int n = 0; n < 13; ++n) o[qt][n] = (f32x4){0.f, 0.f, 0.f, 0.f};
        m[qt] = -1e30f; ell[qt] = 0.f;
    }

    if (wave == 0) stage(0, 0);
    __syncthreads();

    for (int kt = 0; kt < 32; ++kt) {
        const int cur = kt & 1;
        if (kt < 31 && wave == ((kt + 1) & 3)) stage(kt + 1, cur ^ 1);

        f32x4 sacc[2][2];
        #pragma unroll
        for (int qt = 0; qt < 2; ++qt)
            #pragma unroll
            for (int t = 0; t < 2; ++t) sacc[qt][t] = (f32x4){0.f, 0.f, 0.f, 0.f};
        __builtin_amdgcn_s_setprio(1);
        #pragma unroll
        for (int t = 0; t < 2; ++t)
            #pragma unroll
            for (int ks = 0; ks < 7; ++ks) {
                short8 kf = *(const short8*)(&Kbuf[cur][(t * 16 + lo) * PSTRIDE + ks * 32 + hi * 8]);
                sacc[0][t] = __builtin_amdgcn_mfma_f32_16x16x32_bf16(kf, qf[0][ks], sacc[0][t], 0, 0, 0);
                sacc[1][t] = __builtin_amdgcn_mfma_f32_16x16x32_bf16(kf, qf[1][ks], sacc[1][t], 0, 0, 0);
            }
        __builtin_amdgcn_s_setprio(0);

        short8 pa[2];
        #pragma unroll
        for (int qt = 0; qt < 2; ++qt) {
            float mx = fmaxf(fmaxf(fmaxf(sacc[qt][0][0], sacc[qt][0][1]),
                                   fmaxf(sacc[qt][0][2], sacc[qt][0][3])),
                             fmaxf(fmaxf(sacc[qt][1][0], sacc[qt][1][1]),
                                   fmaxf(sacc[qt][1][2], sacc[qt][1][3])));
            mx = fmaxf(mx, __shfl_xor(mx, 16));
            mx = fmaxf(mx, __shfl_xor(mx, 32));
            if (__any(mx > m[qt] + 11.5f)) {          // T13 defer-max (log2 units)
                float mn = fmaxf(m[qt], mx);
                float al = exp2f(m[qt] - mn);
                m[qt] = mn; ell[qt] *= al;
                float alr[4];
                #pragma unroll
                for (int r = 0; r < 4; ++r) alr[r] = __shfl(al, hi * 4 + r);
                #pragma unroll
                for (int n = 0; n < 13; ++n)
                    #pragma unroll
                    for (int r = 0; r < 4; ++r) o[qt][n][r] *= alr[r];
            }
            float p[2][4]; float rsum = 0.f;
            #pragma unroll
            for (int t = 0; t < 2; ++t)
                #pragma unroll
                for (int r = 0; r < 4; ++r) {
                    p[t][r] = exp2f(sacc[qt][t][r] - m[qt]);
                    rsum += p[t][r];
                }
            rsum += __shfl_xor(rsum, 16);
            rsum += __shfl_xor(rsum, 32);
            ell[qt] += rsum;
            unsigned pk01_0 = cvtpk_bf16(p[0][0], p[0][1]);
            unsigned pk23_0 = cvtpk_bf16(p[0][2], p[0][3]);
            unsigned pk01_1 = cvtpk_bf16(p[1][0], p[1][1]);
            unsigned pk23_1 = cvtpk_bf16(p[1][2], p[1][3]);
            const int srcA = lo + ((hi & 1) * 2) * 16;
            const int srcB = srcA + 16;
            int a0 = __shfl((int)pk01_0, srcA), a1 = __shfl((int)pk01_1, srcA);
            int b0 = __shfl((int)pk23_0, srcA), b1 = __shfl((int)pk23_1, srcA);
            int c0 = __shfl((int)pk01_0, srcB), c1 = __shfl((int)pk01_1, srcB);
            int d0 = __shfl((int)pk23_0, srcB), d1 = __shfl((int)pk23_1, srcB);
            const bool thi = (hi >> 1) != 0;
            union { short8 s; int u[4]; } pu;
            pu.u[0] = thi ? a1 : a0;
            pu.u[1] = thi ? b1 : b0;
            pu.u[2] = thi ? c1 : c0;
            pu.u[3] = thi ? d1 : d0;
            pa[qt] = pu.s;
        }

        __builtin_amdgcn_s_setprio(1);
        #pragma unroll
        for (int n = 0; n < 13; ++n) {
            int d = n * 16 + lo;
            int addr = d * 32 + ((hi * 8) ^ (((d >> 1) & 3) << 3));
            short8 vf = *(const short8*)(&Vbuf[cur][addr]);
            o[0][n] = __builtin_amdgcn_mfma_f32_16x16x32_bf16(pa[0], vf, o[0][n], 0, 0, 0);
            o[1][n] = __builtin_amdgcn_mfma_f32_16x16x32_bf16(pa[1], vf, o[1][n], 0, 0, 0);
        }
        __builtin_amdgcn_s_setprio(0);

        __syncthreads();
    }

    #pragma unroll
    for (int qt = 0; qt < 2; ++qt) {
        float inv_l = 1.f / ell[qt];
        float invr[4];
        #pragma unroll
        for (int r = 0; r < 4; ++r) invr[r] = __shfl(inv_l, hi * 4 + r);
        #pragma unroll
        for (int n = 0; n < 13; ++n) {
            int dcol = n * 16 + lo;
            #pragma unroll
            for (int r = 0; r < 4; ++r) {
                size_t row = (size_t)b * SDIM + q0 + wave * 32 + qt * 16 + hi * 4 + r;
                c[row * DPAD + dcol] = f2bf(o[qt][n][r] * invr[r]);
            }
        }
        #pragma unroll
        for (int r = 0; r < 4; ++r) {
            size_t row = (size_t)b * SDIM + q0 + wave * 32 + qt * 16 + hi * 4 + r;
            c[row * DPAD + 208 + lo] = 0;
        }
    }
}

// ---------------- final: normalize row S-1 only + head ----------------
__global__ void final_kernel(const short* __restrict__ y, const float* __restrict__ parts,
                             const float* __restrict__ Wd, const float* __restrict__ bd,
                             float* __restrict__ out)
{
    const int b = blockIdx.x;
    const float sum = parts[b * 2], sq = parts[b * 2 + 1];
    const float mean = sum / LN_N;
    const float inv  = rsqrtf(sq / LN_N - mean * mean + EPS);
    __shared__ float hrow[DDIM];
    const short* row = y + ((size_t)b * SDIM + SDIM - 1) * DPAD;
    for (int d = threadIdx.x; d < DDIM; d += blockDim.x)
        hrow[d] = (bf2f(row[d]) - mean) * inv;
    __syncthreads();
    if (threadIdx.x < CDIM) {
        float acc = bd[threadIdx.x];
        for (int d = 0; d < DDIM; ++d)
            acc = fmaf(hrow[d], Wd[(size_t)d * CDIM + threadIdx.x], acc);
        out[(size_t)b * CDIM + threadIdx.x] = acc;
    }
}

extern "C" void kernel_launch(void* const* d_in, const int* in_sizes, int n_in,
                              void* d_out, int out_size, void* d_ws, size_t ws_size,
                              hipStream_t stream)
{
    const int*   x     = (const int*)  d_in[0];
    const float* embed = (const float*)d_in[1];
    const float* pos   = (const float*)d_in[2];
    const float* Wp    = (const float*)d_in[3];
    const float* bp    = (const float*)d_in[4];
    const float* Wm    = (const float*)d_in[5];
    const float* bm    = (const float*)d_in[6];
    const float* W1    = (const float*)d_in[7];
    const float* b1    = (const float*)d_in[8];
    const float* W2    = (const float*)d_in[9];
    const float* b2    = (const float*)d_in[10];
    const float* Wd    = (const float*)d_in[11];
    const float* bd    = (const float*)d_in[12];
    float* out = (float*)d_out;

    const size_t HB = (size_t)BDIM * SDIM * DPAD;     // 14,680,064 bf16 elems
    const size_t PB = (size_t)BDIM * SDIM * PSTRIDE;  // p_bf with stride 232

    short* h_bf  = (short*)d_ws;
    short* p_bf  = h_bf  + HB;
    short* pt    = p_bf  + PB;
    short* cb_bf = pt    + HB;
    short* yA    = cb_bf + HB;
    short* yB    = yA    + HB;
    short* WtP   = yB + HB;
    short* WtM   = WtP + DPAD * DPAD;
    short* Wt1   = WtM + DPAD * DPAD;
    short* Wt2   = Wt1 + DPAD * DPAD;
    float* bpP   = (float*)(Wt2 + DPAD * DPAD);
    float* bmP   = bpP + DPAD;
    float* b1P   = bmP + DPAD;
    float* b2P   = b1P + DPAD;
    float* csP   = b2P + DPAD;
    float* cs1   = csP + DPAD;
    float* parts = cs1 + DPAD;                        // 4 x 64 x 2 floats
    const size_t need = (size_t)((char*)(parts + 4 * BDIM * 2) - (char*)d_ws);
    if (ws_size < need) return;

    float* pA1 = parts;
    float* pB1 = parts + BDIM * 2;
    float* pA2 = parts + 2 * BDIM * 2;
    float* pB2 = parts + 3 * BDIM * 2;

    prep_kernel<<<dim3((DPAD * DPAD + 255) / 256), dim3(256), 0, stream>>>(
        Wp, bp, Wm, bm, W1, b1, W2, b2, WtP, WtM, Wt1, Wt2, bpP, bmP, b1P, b2P, csP, cs1);
    embed_kernel<<<dim3(BDIM * SDIM), dim3(256), 0, stream>>>(x, embed, pos, h_bf);
    hipMemsetAsync(parts, 0, 4 * BDIM * 2 * sizeof(float), stream);

    const float qscale = 1.44269504f / sqrtf((float)DDIM);
    const dim3 tgrid(SDIM / 32, DPAD / 32, BDIM);

    // stack 1
    gemm_bf<<<dim3(512), dim3(256), 0, stream>>>(h_bf, nullptr, WtP, bpP, nullptr,
                                                 nullptr, nullptr, p_bf, nullptr, 0, PSTRIDE);
    vt_kernel<<<tgrid, dim3(256), 0, stream>>>(p_bf, pt);
    attn_kernel<<<dim3(512), dim3(256), 0, stream>>>(p_bf, pt, cb_bf, qscale);
    gemm_bf<<<dim3(512), dim3(256), 0, stream>>>(cb_bf, nullptr, WtM, bmP, nullptr,
                                                 h_bf, nullptr, yA, pA1, 0, DPAD);
    gemm_bf<<<dim3(512), dim3(256), 0, stream>>>(yA, pA1, Wt1, b1P, cs1,
                                                 nullptr, nullptr, cb_bf, nullptr, 1, DPAD);
    gemm_bf<<<dim3(512), dim3(256), 0, stream>>>(cb_bf, nullptr, Wt2, b2P, nullptr,
                                                 yA, pA1, yB, pB1, 0, DPAD);
    // stack 2
    gemm_bf<<<dim3(512), dim3(256), 0, stream>>>(yB, pB1, WtP, bpP, csP,
                                                 nullptr, nullptr, p_bf, nullptr, 0, PSTRIDE);
    vt_kernel<<<tgrid, dim3(256), 0, stream>>>(p_bf, pt);
    attn_kernel<<<dim3(512), dim3(256), 0, stream>>>(p_bf, pt, cb_bf, qscale);
    gemm_bf<<<dim3(512), dim3(256), 0, stream>>>(cb_bf, nullptr, WtM, bmP, nullptr,
                                                 yB, pB1, h_bf, pA2, 0, DPAD);
    gemm_bf<<<dim3(512), dim3(256), 0, stream>>>(h_bf, pA2, Wt1, b1P, cs1,
                                                 nullptr, nullptr, cb_bf, nullptr, 1, DPAD);
    gemm_bf<<<dim3(512), dim3(256), 0, stream>>>(cb_bf, nullptr, Wt2, b2P, nullptr,
                                                 h_bf, pA2, yA, pB2, 0, DPAD);
    final_kernel<<<dim3(BDIM), dim3(64), 0, stream>>>(yA, pB2, Wd, bd, out);
}